// Round 1
// 11235.554 us; speedup vs baseline: 1.1233x; 1.1233x over previous
//
#include <hip/hip_runtime.h>
#include <stdint.h>

#define B_ 32
#define T_ 256
#define DI_ 512
#define H_ 1024

using f32x4 = __attribute__((ext_vector_type(4))) float;
using s16x8 = __attribute__((ext_vector_type(8))) short;

__device__ inline unsigned short f2bf(float x) {
    unsigned u = __float_as_uint(x);
    u += 0x7FFFu + ((u >> 16) & 1u);
    return (unsigned short)(u >> 16);
}
__device__ inline float bf2f(unsigned short h) { return __uint_as_float(((unsigned)h) << 16); }
__device__ inline float sigf(float x) { return 1.f / (1.f + __expf(-x)); }
__device__ inline float tanhf_(float x) { return 1.f - 2.f / (__expf(2.f * x) + 1.f); }

// coherent (agent-scope, sc1) 16B load: 2 x 8B relaxed atomic loads.
// Bypasses the non-coherent per-XCD L2 -> reads LLC. No fence needed.
__device__ inline s16x8 ld16c(const unsigned short* p) {
    union { unsigned long long u[2]; s16x8 v; } r;
    const unsigned long long* q = (const unsigned long long*)p;
    r.u[0] = __hip_atomic_load(q, __ATOMIC_RELAXED, __HIP_MEMORY_SCOPE_AGENT);
    r.u[1] = __hip_atomic_load(q + 1, __ATOMIC_RELAXED, __HIP_MEMORY_SCOPE_AGENT);
    return r.v;
}

// ---------------- conversion kernels ----------------

// inputs (B,T,DI) fp32 -> A0 [(t*B+b)][DI] bf16
__global__ void conv_inputs_k(const float* __restrict__ in, unsigned short* __restrict__ out) {
    int idx = blockIdx.x * 256 + threadIdx.x;
    int d = (idx & 127) * 4;
    int row = idx >> 7;
    int t = row >> 5, b = row & 31;
    float4 v = *(const float4*)(in + ((size_t)b * T_ + t) * DI_ + d);
    unsigned long long p = (unsigned long long)f2bf(v.x)
        | ((unsigned long long)f2bf(v.y) << 16)
        | ((unsigned long long)f2bf(v.z) << 32)
        | ((unsigned long long)f2bf(v.w) << 48);
    *(unsigned long long*)(out + (size_t)row * DI_ + d) = p;
}

// generic fp32 [R][rowStride] (col offset) -> bf16 [R][K]
__global__ void conv_w_k(const float* __restrict__ src, unsigned short* __restrict__ dst,
                         int rowStride, int colOff, int K, int total4) {
    int idx = blockIdx.x * 256 + threadIdx.x;
    if (idx >= total4) return;
    int K4 = K >> 2;
    int r = idx / K4;
    int k = (idx - r * K4) << 2;
    float4 v = *(const float4*)(src + (size_t)r * rowStride + colOff + k);
    unsigned long long p = (unsigned long long)f2bf(v.x)
        | ((unsigned long long)f2bf(v.y) << 16)
        | ((unsigned long long)f2bf(v.z) << 32)
        | ((unsigned long long)f2bf(v.w) << 48);
    *(unsigned long long*)(dst + (size_t)r * K + k) = p;
}

__global__ void bias0_k(const float* __restrict__ a, const float* __restrict__ b, float* __restrict__ o) {
    int i = blockIdx.x * 256 + threadIdx.x;
    if (i < 4 * H_) o[i] = a[i] + b[i];
}

// ---------------- big parallel projection GEMM ----------------
__global__ __launch_bounds__(256) void proj_gemm_k(
    const unsigned short* __restrict__ A, const unsigned short* __restrict__ W,
    const float* __restrict__ bias, unsigned short* __restrict__ out, int K, int N) {
    __shared__ unsigned short Al[128 * 56];
    __shared__ unsigned short Bl[128 * 56];
    const int tid = threadIdx.x;
    const int lane = tid & 63, wave = tid >> 6;
    const int quad = lane >> 4, l16 = lane & 15;
    const int wm = (wave >> 1) * 64, wn = (wave & 1) * 64;
    const int bm = blockIdx.x, bn = blockIdx.y;
    const int srow = tid >> 1, shalf = tid & 1;
    const unsigned short* Ab = A + (size_t)(bm * 128 + srow) * K + shalf * 16;
    const unsigned short* Wb = W + (size_t)(bn * 128 + srow) * K + shalf * 16;

    f32x4 acc[4][4];
#pragma unroll
    for (int i = 0; i < 4; i++)
#pragma unroll
        for (int j = 0; j < 4; j++) acc[i][j] = (f32x4){0.f, 0.f, 0.f, 0.f};

    for (int kb = 0; kb < K; kb += 32) {
        s16x8 a0 = *(const s16x8*)(Ab + kb);
        s16x8 a1 = *(const s16x8*)(Ab + kb + 8);
        s16x8 b0 = *(const s16x8*)(Wb + kb);
        s16x8 b1 = *(const s16x8*)(Wb + kb + 8);
        __syncthreads();
        *(s16x8*)(&Al[srow * 56 + shalf * 16]) = a0;
        *(s16x8*)(&Al[srow * 56 + shalf * 16 + 8]) = a1;
        *(s16x8*)(&Bl[srow * 56 + shalf * 16]) = b0;
        *(s16x8*)(&Bl[srow * 56 + shalf * 16 + 8]) = b1;
        __syncthreads();
        s16x8 af[4], bf[4];
#pragma unroll
        for (int mt = 0; mt < 4; mt++) af[mt] = *(const s16x8*)(&Al[(wm + mt * 16 + l16) * 56 + quad * 8]);
#pragma unroll
        for (int nt = 0; nt < 4; nt++) bf[nt] = *(const s16x8*)(&Bl[(wn + nt * 16 + l16) * 56 + quad * 8]);
#pragma unroll
        for (int mt = 0; mt < 4; mt++)
#pragma unroll
            for (int nt = 0; nt < 4; nt++)
                acc[mt][nt] = __builtin_amdgcn_mfma_f32_16x16x32_bf16(af[mt], bf[nt], acc[mt][nt], 0, 0, 0);
    }
#pragma unroll
    for (int nt = 0; nt < 4; nt++) {
        int col = bn * 128 + wn + nt * 16 + l16;
        float bv = bias[col];
#pragma unroll
        for (int mt = 0; mt < 4; mt++) {
#pragma unroll
            for (int r = 0; r < 4; r++) {
                int rowg = bm * 128 + wm + mt * 16 + quad * 4 + r;
                out[(size_t)rowg * N + col] = f2bf(acc[mt][nt][r] + bv);
            }
        }
    }
}

// ---------------- persistent recurrence kernel (fence-free) ----------------
// Per-step structure:
//   wave w polls ONLY flags[w*64+lane] (1x4B agent load/lane) -> 16x less flag
//   traffic than all-wave/all-flag polling, and wave w can start staging as
//   soon as its own 64 producers are done.
//   wave w stages h(t-1) cols [w*256, w*256+256) into LDS (coalesced 16B),
//   MFMA A-fragments then read from LDS (halves LLC h traffic, removes LLC
//   latency from the MFMA chain).
template <int NG, bool CA, bool WROUT>
__global__ __launch_bounds__(256) void rec_k(
    const float* __restrict__ Wsrc, int wRowStride, int wColOff,
    const unsigned short* __restrict__ pre, int N,
    const unsigned short* __restrict__ clow,
    unsigned short* __restrict__ hbuf,
    unsigned short* __restrict__ cbuf,
    float* __restrict__ outh, float* __restrict__ outc,
    unsigned* __restrict__ flags) {
    constexpr int ROWS = NG * 4;
    __shared__ unsigned short wl[(ROWS + 1) * 1032];
    __shared__ unsigned short hl[32 * 1032];   // staged h(t-1), padded stride
    __shared__ float gl[32 * 24];
    __shared__ alignas(8) unsigned short hsh[128];
    const int tid = threadIdx.x;
    const int wg = blockIdx.x;
    const int lane = tid & 63, wave = tid >> 6;
    const int quad = lane >> 4, l16 = lane & 15;

    // load + convert this WG's weight rows into LDS
    for (int i = tid; i < ROWS * 1024; i += 256) {
        int r = i >> 10, k = i & 1023;
        int g = r >> 2, u2 = r & 3;
        float wv = Wsrc[(size_t)(g * H_ + wg * 4 + u2) * wRowStride + wColOff + k];
        wl[r * 1032 + k] = f2bf(wv);
    }
    for (int k = tid; k < 1032; k += 256) wl[ROWS * 1032 + k] = 0;

    const int mtile = wave & 1;
    const int ntile = wave >> 1;
    const bool active = (ntile * 16) < ROWS;
    int brow = ntile * 16 + l16;
    if (brow >= ROWS) brow = ROWS;  // zero row for padded N-columns

    // staging geometry: wave covers h cols [wave*256, wave*256+256)
    const int scol = wave * 256 + (lane & 31) * 8;
    const int srow0 = lane >> 5;

    const int u = tid & 3, b = tid >> 2;  // pointwise ownership (tid < 128)
    const int unit = wg * 4 + u;
    float cst = 0.f;
    unsigned short pg[NG];
    unsigned short clw = 0;
    if (tid < 128) {
#pragma unroll
        for (int g = 0; g < NG; g++) pg[g] = pre[(size_t)b * N + g * H_ + unit];
        if (CA) clw = clow[(size_t)b * H_ + unit];
    }
    __syncthreads();  // wl ready

    for (int t = 0; t < T_; ++t) {
        if (t > 0) {
            unsigned tgt = (unsigned)t;
            const unsigned* fp = flags + wave * 64 + lane;
            for (;;) {
                unsigned f = __hip_atomic_load(fp, __ATOMIC_RELAXED, __HIP_MEMORY_SCOPE_AGENT);
                if (__all((int)(f >= tgt))) break;
                __builtin_amdgcn_s_sleep(1);
            }
            asm volatile("" ::: "memory");  // keep h loads after poll
            // stage this wave's slice of h(t-1) into LDS (coalesced 16B chunks)
            const unsigned short* hbase = hbuf + (size_t)(t - 1) * (B_ * H_);
#pragma unroll
            for (int i = 0; i < 16; i++) {
                int row = srow0 + 2 * i;
                s16x8 v = ld16c(hbase + (size_t)row * H_ + scol);
                *(s16x8*)(&hl[row * 1032 + scol]) = v;
            }
        }
        __syncthreads();  // hl fully staged
        if (t > 0 && active) {
            const unsigned short* arow = &hl[(mtile * 16 + l16) * 1032 + quad * 8];
            const unsigned short* wrow = &wl[brow * 1032 + quad * 8];
            f32x4 a0 = (f32x4){0.f, 0.f, 0.f, 0.f};
            f32x4 a1 = a0, a2 = a0, a3 = a0;
#pragma unroll
            for (int kb = 0; kb < H_; kb += 128) {
                a0 = __builtin_amdgcn_mfma_f32_16x16x32_bf16(*(const s16x8*)(arow + kb), *(const s16x8*)(wrow + kb), a0, 0, 0, 0);
                a1 = __builtin_amdgcn_mfma_f32_16x16x32_bf16(*(const s16x8*)(arow + kb + 32), *(const s16x8*)(wrow + kb + 32), a1, 0, 0, 0);
                a2 = __builtin_amdgcn_mfma_f32_16x16x32_bf16(*(const s16x8*)(arow + kb + 64), *(const s16x8*)(wrow + kb + 64), a2, 0, 0, 0);
                a3 = __builtin_amdgcn_mfma_f32_16x16x32_bf16(*(const s16x8*)(arow + kb + 96), *(const s16x8*)(wrow + kb + 96), a3, 0, 0, 0);
            }
            f32x4 acc = (a0 + a1) + (a2 + a3);
            int n = ntile * 16 + l16;
            if (n < ROWS) {
#pragma unroll
                for (int r = 0; r < 4; r++) gl[(mtile * 16 + quad * 4 + r) * 24 + n] = acc[r];
            }
        }
        __syncthreads();  // gl ready
        if (tid < 128) {
            float gate[NG];
#pragma unroll
            for (int g = 0; g < NG; g++)
                gate[g] = bf2f(pg[g]) + ((t > 0) ? gl[b * 24 + g * 4 + u] : 0.f);
            float clv = CA ? bf2f(clw) : 0.f;
            if (t + 1 < T_) {  // prefetch next step's pre / c_low
#pragma unroll
                for (int g = 0; g < NG; g++) pg[g] = pre[(size_t)((t + 1) * B_ + b) * N + g * H_ + unit];
                if (CA) clw = clow[(size_t)((t + 1) * B_ + b) * H_ + unit];
            }
            float cnew, hval;
            if (CA) {
                float iv = sigf(gate[0]);
                float fp = sigf(gate[1] + 1.f);
                float fl = sigf(gate[2] + 1.f);
                float uu = tanhf_(gate[3]);
                float ov = sigf(gate[4]);
                cnew = cst * fp + clv * fl + uu * iv;
                hval = ov * tanhf_(cnew);
            } else {
                float iv = sigf(gate[0]);
                float fv = sigf(gate[1]);
                float gv = tanhf_(gate[2]);
                float ov = sigf(gate[3]);
                cnew = fv * cst + iv * gv;
                hval = ov * tanhf_(cnew);
            }
            cst = cnew;
            hsh[tid] = f2bf(hval);
            size_t ridx = ((size_t)t * B_ + b) * H_ + unit;
            if (cbuf) cbuf[ridx] = f2bf(cnew);  // plain store: consumed by a later dispatch only
            if (WROUT) {
                outh[((size_t)b * T_ + t) * H_ + unit] = hval;
                outc[((size_t)b * T_ + t) * H_ + unit] = cnew;
            }
        }
        __syncthreads();  // hsh ready
        // wave 0: pack 4 bf16 -> 8B coherent store, then release via vmcnt(0) + flag
        if (tid < 32) {
            unsigned long long pk = *(const unsigned long long*)(&hsh[tid * 4]);
            unsigned long long* dst = (unsigned long long*)(hbuf + ((size_t)t * B_ + tid) * H_ + wg * 4);
            __hip_atomic_store(dst, pk, __ATOMIC_RELAXED, __HIP_MEMORY_SCOPE_AGENT);
        }
        if (wave == 0) {
            asm volatile("s_waitcnt vmcnt(0)" ::: "memory");  // h stores visible at LLC
            if (tid == 0)
                __hip_atomic_store(&flags[wg], (unsigned)(t + 1), __ATOMIC_RELAXED, __HIP_MEMORY_SCOPE_AGENT);
        }
    }
}

// ---------------- launcher ----------------

extern "C" void kernel_launch(void* const* d_in, const int* in_sizes, int n_in,
                              void* d_out, int out_size, void* d_ws, size_t ws_size,
                              hipStream_t stream) {
    const float* inputs = (const float*)d_in[0];
    const float* W_ih0 = (const float*)d_in[1];
    const float* W_hh0 = (const float*)d_in[2];
    const float* b_ih0 = (const float*)d_in[3];
    const float* b_hh0 = (const float*)d_in[4];
    const float* W_ca = (const float*)d_in[5];
    const float* b_ca = (const float*)d_in[6];
    float* out = (float*)d_out;

    char* ws = (char*)d_ws;
    unsigned* flags = (unsigned*)(ws);                                       //  4 KB
    unsigned short* A0 = (unsigned short*)(ws + 4096);                       //  8 MB
    unsigned short* Wbuf = (unsigned short*)(ws + 4096 + 8388608);           // 10.5 MB
    float* bc0 = (float*)(ws + 4096 + 8388608 + 10485760);                   // 16 KB
    unsigned short* pre = (unsigned short*)(ws + 4096 + 8388608 + 10485760 + 16384);  // 84 MB
    unsigned short* hA = pre + (size_t)8192 * 5120;
    unsigned short* hB = hA + (size_t)8192 * 1024;
    unsigned short* cA = hB + (size_t)8192 * 1024;
    unsigned short* cB = cA + (size_t)8192 * 1024;

    hipMemsetAsync(flags, 0, 4096, stream);

    // layer 0
    conv_inputs_k<<<4096, 256, 0, stream>>>(inputs, A0);
    conv_w_k<<<2048, 256, 0, stream>>>(W_ih0, Wbuf, 512, 0, 512, 4096 * 128);
    bias0_k<<<16, 256, 0, stream>>>(b_ih0, b_hh0, bc0);
    proj_gemm_k<<<dim3(64, 32), 256, 0, stream>>>(A0, Wbuf, bc0, pre, 512, 4096);
    rec_k<4, false, false><<<256, 256, 0, stream>>>(W_hh0, 1024, 0, pre, 4096, nullptr,
                                                    hA, cA, nullptr, nullptr, flags + 0);
    // layer 1
    conv_w_k<<<5120, 256, 0, stream>>>(W_ca + (size_t)0 * 5120 * 2048, Wbuf, 2048, 0, 1024, 5120 * 256);
    proj_gemm_k<<<dim3(64, 40), 256, 0, stream>>>(hA, Wbuf, b_ca + 0 * 5120, pre, 1024, 5120);
    rec_k<5, true, false><<<256, 256, 0, stream>>>(W_ca + (size_t)0 * 5120 * 2048, 2048, 1024, pre, 5120,
                                                   cA, hB, cB, nullptr, nullptr, flags + 256);
    // layer 2
    conv_w_k<<<5120, 256, 0, stream>>>(W_ca + (size_t)1 * 5120 * 2048, Wbuf, 2048, 0, 1024, 5120 * 256);
    proj_gemm_k<<<dim3(64, 40), 256, 0, stream>>>(hB, Wbuf, b_ca + 1 * 5120, pre, 1024, 5120);
    rec_k<5, true, false><<<256, 256, 0, stream>>>(W_ca + (size_t)1 * 5120 * 2048, 2048, 1024, pre, 5120,
                                                   cB, hA, cA, nullptr, nullptr, flags + 512);
    // layer 3 (writes d_out directly: hs then cs, (B,T,H) fp32)
    conv_w_k<<<5120, 256, 0, stream>>>(W_ca + (size_t)2 * 5120 * 2048, Wbuf, 2048, 0, 1024, 5120 * 256);
    proj_gemm_k<<<dim3(64, 40), 256, 0, stream>>>(hA, Wbuf, b_ca + 2 * 5120, pre, 1024, 5120);
    rec_k<5, true, true><<<256, 256, 0, stream>>>(W_ca + (size_t)2 * 5120 * 2048, 2048, 1024, pre, 5120,
                                                  cA, hB, nullptr, out, out + (size_t)8192 * 1024, flags + 768);
}

// Round 2
// 7827.684 us; speedup vs baseline: 1.6123x; 1.4354x over previous
//
#include <hip/hip_runtime.h>
#include <stdint.h>

#define B_ 32
#define T_ 256
#define DI_ 512
#define H_ 1024

using f32x4 = __attribute__((ext_vector_type(4))) float;
using s16x8 = __attribute__((ext_vector_type(8))) short;

__device__ inline unsigned short f2bf(float x) {
    unsigned u = __float_as_uint(x);
    u += 0x7FFFu + ((u >> 16) & 1u);
    return (unsigned short)(u >> 16);
}
__device__ inline float bf2f(unsigned short h) { return __uint_as_float(((unsigned)h) << 16); }
__device__ inline float sigf(float x) { return 1.f / (1.f + __expf(-x)); }
__device__ inline float tanhf_(float x) { return 1.f - 2.f / (__expf(2.f * x) + 1.f); }

// ---------------- conversion kernels ----------------

// inputs (B,T,DI) fp32 -> A0 [(t*B+b)][DI] bf16
__global__ void conv_inputs_k(const float* __restrict__ in, unsigned short* __restrict__ out) {
    int idx = blockIdx.x * 256 + threadIdx.x;
    int d = (idx & 127) * 4;
    int row = idx >> 7;
    int t = row >> 5, b = row & 31;
    float4 v = *(const float4*)(in + ((size_t)b * T_ + t) * DI_ + d);
    unsigned long long p = (unsigned long long)f2bf(v.x)
        | ((unsigned long long)f2bf(v.y) << 16)
        | ((unsigned long long)f2bf(v.z) << 32)
        | ((unsigned long long)f2bf(v.w) << 48);
    *(unsigned long long*)(out + (size_t)row * DI_ + d) = p;
}

// generic fp32 [R][rowStride] (col offset) -> bf16 [R][K]
__global__ void conv_w_k(const float* __restrict__ src, unsigned short* __restrict__ dst,
                         int rowStride, int colOff, int K, int total4) {
    int idx = blockIdx.x * 256 + threadIdx.x;
    if (idx >= total4) return;
    int K4 = K >> 2;
    int r = idx / K4;
    int k = (idx - r * K4) << 2;
    float4 v = *(const float4*)(src + (size_t)r * rowStride + colOff + k);
    unsigned long long p = (unsigned long long)f2bf(v.x)
        | ((unsigned long long)f2bf(v.y) << 16)
        | ((unsigned long long)f2bf(v.z) << 32)
        | ((unsigned long long)f2bf(v.w) << 48);
    *(unsigned long long*)(dst + (size_t)r * K + k) = p;
}

__global__ void bias0_k(const float* __restrict__ a, const float* __restrict__ b, float* __restrict__ o) {
    int i = blockIdx.x * 256 + threadIdx.x;
    if (i < 4 * H_) o[i] = a[i] + b[i];
}

// ---------------- big parallel projection GEMM ----------------
__global__ __launch_bounds__(256) void proj_gemm_k(
    const unsigned short* __restrict__ A, const unsigned short* __restrict__ W,
    const float* __restrict__ bias, unsigned short* __restrict__ out, int K, int N) {
    __shared__ unsigned short Al[128 * 56];
    __shared__ unsigned short Bl[128 * 56];
    const int tid = threadIdx.x;
    const int lane = tid & 63, wave = tid >> 6;
    const int quad = lane >> 4, l16 = lane & 15;
    const int wm = (wave >> 1) * 64, wn = (wave & 1) * 64;
    const int bm = blockIdx.x, bn = blockIdx.y;
    const int srow = tid >> 1, shalf = tid & 1;
    const unsigned short* Ab = A + (size_t)(bm * 128 + srow) * K + shalf * 16;
    const unsigned short* Wb = W + (size_t)(bn * 128 + srow) * K + shalf * 16;

    f32x4 acc[4][4];
#pragma unroll
    for (int i = 0; i < 4; i++)
#pragma unroll
        for (int j = 0; j < 4; j++) acc[i][j] = (f32x4){0.f, 0.f, 0.f, 0.f};

    for (int kb = 0; kb < K; kb += 32) {
        s16x8 a0 = *(const s16x8*)(Ab + kb);
        s16x8 a1 = *(const s16x8*)(Ab + kb + 8);
        s16x8 b0 = *(const s16x8*)(Wb + kb);
        s16x8 b1 = *(const s16x8*)(Wb + kb + 8);
        __syncthreads();
        *(s16x8*)(&Al[srow * 56 + shalf * 16]) = a0;
        *(s16x8*)(&Al[srow * 56 + shalf * 16 + 8]) = a1;
        *(s16x8*)(&Bl[srow * 56 + shalf * 16]) = b0;
        *(s16x8*)(&Bl[srow * 56 + shalf * 16 + 8]) = b1;
        __syncthreads();
        s16x8 af[4], bf[4];
#pragma unroll
        for (int mt = 0; mt < 4; mt++) af[mt] = *(const s16x8*)(&Al[(wm + mt * 16 + l16) * 56 + quad * 8]);
#pragma unroll
        for (int nt = 0; nt < 4; nt++) bf[nt] = *(const s16x8*)(&Bl[(wn + nt * 16 + l16) * 56 + quad * 8]);
#pragma unroll
        for (int mt = 0; mt < 4; mt++)
#pragma unroll
            for (int nt = 0; nt < 4; nt++)
                acc[mt][nt] = __builtin_amdgcn_mfma_f32_16x16x32_bf16(af[mt], bf[nt], acc[mt][nt], 0, 0, 0);
    }
#pragma unroll
    for (int nt = 0; nt < 4; nt++) {
        int col = bn * 128 + wn + nt * 16 + l16;
        float bv = bias[col];
#pragma unroll
        for (int mt = 0; mt < 4; mt++) {
#pragma unroll
            for (int r = 0; r < 4; r++) {
                int rowg = bm * 128 + wm + mt * 16 + quad * 4 + r;
                out[(size_t)rowg * N + col] = f2bf(acc[mt][nt][r] + bv);
            }
        }
    }
}

// ---------------- persistent recurrence kernel (fence-free) ----------------
// h-exchange coherence design:
//   producers store h with sc1 (agent-scope) -> value lands at LLC, release
//   via s_waitcnt vmcnt(0) then flag store (sc1).
//   consumers poll flags with sc1 loads (must never hit a non-coherent L2),
//   but stage h(t-1) with PLAIN CACHED loads: hbuf is indexed by t, so each
//   step reads a fresh address region first touched only after the flag poll
//   -> no stale L1/L2 copy can exist within the dispatch; cross-dispatch
//   staleness is handled by the dispatch-boundary L2 invalidate. The 32 WGs
//   sharing an XCD then de-duplicate the h broadcast through the XCD L2:
//   LLC read traffic drops from Nwg*64KB to ~8*64KB per step.
template <int NG, bool CA, bool WROUT>
__global__ __launch_bounds__(256) void rec_k(
    const float* __restrict__ Wsrc, int wRowStride, int wColOff,
    const unsigned short* __restrict__ pre, int N,
    const unsigned short* __restrict__ clow,
    unsigned short* __restrict__ hbuf,
    unsigned short* __restrict__ cbuf,
    float* __restrict__ outh, float* __restrict__ outc,
    unsigned* __restrict__ flags) {
    constexpr int ROWS = NG * 4;
    __shared__ unsigned short wl[(ROWS + 1) * 1032];
    __shared__ unsigned short hl[32 * 1032];   // staged h(t-1), padded stride
    __shared__ float gl[32 * 25];
    __shared__ alignas(8) unsigned short hsh[128];
    const int tid = threadIdx.x;
    const int wg = blockIdx.x;
    const int lane = tid & 63, wave = tid >> 6;
    const int quad = lane >> 4, l16 = lane & 15;

    // load + convert this WG's weight rows into LDS
    for (int i = tid; i < ROWS * 1024; i += 256) {
        int r = i >> 10, k = i & 1023;
        int g = r >> 2, u2 = r & 3;
        float wv = Wsrc[(size_t)(g * H_ + wg * 4 + u2) * wRowStride + wColOff + k];
        wl[r * 1032 + k] = f2bf(wv);
    }
    for (int k = tid; k < 1032; k += 256) wl[ROWS * 1032 + k] = 0;

    const int mtile = wave & 1;
    const int ntile = wave >> 1;
    const bool active = (ntile * 16) < ROWS;
    int brow = ntile * 16 + l16;
    if (brow >= ROWS) brow = ROWS;  // zero row for padded N-columns

    // staging geometry: wave covers h cols [wave*256, wave*256+256)
    const int scol = wave * 256 + (lane & 31) * 8;
    const int srow0 = lane >> 5;

    const int u = tid & 3, b = tid >> 2;  // pointwise ownership (tid < 128)
    const int unit = wg * 4 + u;
    float cst = 0.f;
    unsigned short pg[NG];
    unsigned short clw = 0;
    if (tid < 128) {
#pragma unroll
        for (int g = 0; g < NG; g++) pg[g] = pre[(size_t)b * N + g * H_ + unit];
        if (CA) clw = clow[(size_t)b * H_ + unit];
    }
    __syncthreads();  // wl ready

    for (int t = 0; t < T_; ++t) {
        if (t > 0) {
            unsigned tgt = (unsigned)t;
            const unsigned* fp = flags + wave * 64 + lane;
            for (;;) {
                unsigned f = __hip_atomic_load(fp, __ATOMIC_RELAXED, __HIP_MEMORY_SCOPE_AGENT);
                if (__all((int)(f >= tgt))) break;
                __builtin_amdgcn_s_sleep(1);
            }
            asm volatile("" ::: "memory");  // keep h loads after poll
            // stage this wave's slice of h(t-1) into LDS.
            // PLAIN cached loads (see header comment): first touch of this
            // address region is post-flag, so L1/L2 cannot be stale, and the
            // XCD L2 de-duplicates the broadcast across the XCD's WGs.
            const unsigned short* hbase = hbuf + (size_t)(t - 1) * (B_ * H_) + scol;
            s16x8 hv[16];
#pragma unroll
            for (int i = 0; i < 16; i++)
                hv[i] = *(const s16x8*)(hbase + (size_t)(srow0 + 2 * i) * H_);
#pragma unroll
            for (int i = 0; i < 16; i++)
                *(s16x8*)(&hl[(srow0 + 2 * i) * 1032 + scol]) = hv[i];
        }
        __syncthreads();  // hl fully staged
        if (t > 0 && active) {
            const unsigned short* arow = &hl[(mtile * 16 + l16) * 1032 + quad * 8];
            const unsigned short* wrow = &wl[brow * 1032 + quad * 8];
            f32x4 a0 = (f32x4){0.f, 0.f, 0.f, 0.f};
            f32x4 a1 = a0, a2 = a0, a3 = a0;
#pragma unroll
            for (int kb = 0; kb < H_; kb += 128) {
                a0 = __builtin_amdgcn_mfma_f32_16x16x32_bf16(*(const s16x8*)(arow + kb), *(const s16x8*)(wrow + kb), a0, 0, 0, 0);
                a1 = __builtin_amdgcn_mfma_f32_16x16x32_bf16(*(const s16x8*)(arow + kb + 32), *(const s16x8*)(wrow + kb + 32), a1, 0, 0, 0);
                a2 = __builtin_amdgcn_mfma_f32_16x16x32_bf16(*(const s16x8*)(arow + kb + 64), *(const s16x8*)(wrow + kb + 64), a2, 0, 0, 0);
                a3 = __builtin_amdgcn_mfma_f32_16x16x32_bf16(*(const s16x8*)(arow + kb + 96), *(const s16x8*)(wrow + kb + 96), a3, 0, 0, 0);
            }
            f32x4 acc = (a0 + a1) + (a2 + a3);
            int n = ntile * 16 + l16;
            if (n < ROWS) {
#pragma unroll
                for (int r = 0; r < 4; r++) gl[(mtile * 16 + quad * 4 + r) * 25 + n] = acc[r];
            }
        }
        __syncthreads();  // gl ready
        if (tid < 128) {
            float gate[NG];
#pragma unroll
            for (int g = 0; g < NG; g++)
                gate[g] = bf2f(pg[g]) + ((t > 0) ? gl[b * 25 + g * 4 + u] : 0.f);
            float clv = CA ? bf2f(clw) : 0.f;
            if (t + 1 < T_) {  // prefetch next step's pre / c_low
#pragma unroll
                for (int g = 0; g < NG; g++) pg[g] = pre[(size_t)((t + 1) * B_ + b) * N + g * H_ + unit];
                if (CA) clw = clow[(size_t)((t + 1) * B_ + b) * H_ + unit];
            }
            float cnew, hval;
            if (CA) {
                float iv = sigf(gate[0]);
                float fp = sigf(gate[1] + 1.f);
                float fl = sigf(gate[2] + 1.f);
                float uu = tanhf_(gate[3]);
                float ov = sigf(gate[4]);
                cnew = cst * fp + clv * fl + uu * iv;
                hval = ov * tanhf_(cnew);
            } else {
                float iv = sigf(gate[0]);
                float fv = sigf(gate[1]);
                float gv = tanhf_(gate[2]);
                float ov = sigf(gate[3]);
                cnew = fv * cst + iv * gv;
                hval = ov * tanhf_(cnew);
            }
            cst = cnew;
            hsh[tid] = f2bf(hval);
            size_t ridx = ((size_t)t * B_ + b) * H_ + unit;
            if (cbuf) cbuf[ridx] = f2bf(cnew);  // plain store: consumed by a later dispatch only
            if (WROUT) {
                outh[((size_t)b * T_ + t) * H_ + unit] = hval;
                outc[((size_t)b * T_ + t) * H_ + unit] = cnew;
            }
        }
        __syncthreads();  // hsh ready
        // wave 0: pack 4 bf16 -> 8B coherent store, then release via vmcnt(0) + flag
        if (tid < 32) {
            unsigned long long pk = *(const unsigned long long*)(&hsh[tid * 4]);
            unsigned long long* dst = (unsigned long long*)(hbuf + ((size_t)t * B_ + tid) * H_ + wg * 4);
            __hip_atomic_store(dst, pk, __ATOMIC_RELAXED, __HIP_MEMORY_SCOPE_AGENT);
        }
        if (wave == 0) {
            asm volatile("s_waitcnt vmcnt(0)" ::: "memory");  // h stores visible at LLC
            if (tid == 0)
                __hip_atomic_store(&flags[wg], (unsigned)(t + 1), __ATOMIC_RELAXED, __HIP_MEMORY_SCOPE_AGENT);
        }
    }
}

// ---------------- launcher ----------------

extern "C" void kernel_launch(void* const* d_in, const int* in_sizes, int n_in,
                              void* d_out, int out_size, void* d_ws, size_t ws_size,
                              hipStream_t stream) {
    const float* inputs = (const float*)d_in[0];
    const float* W_ih0 = (const float*)d_in[1];
    const float* W_hh0 = (const float*)d_in[2];
    const float* b_ih0 = (const float*)d_in[3];
    const float* b_hh0 = (const float*)d_in[4];
    const float* W_ca = (const float*)d_in[5];
    const float* b_ca = (const float*)d_in[6];
    float* out = (float*)d_out;

    char* ws = (char*)d_ws;
    unsigned* flags = (unsigned*)(ws);                                       //  4 KB
    unsigned short* A0 = (unsigned short*)(ws + 4096);                       //  8 MB
    unsigned short* Wbuf = (unsigned short*)(ws + 4096 + 8388608);           // 10.5 MB
    float* bc0 = (float*)(ws + 4096 + 8388608 + 10485760);                   // 16 KB
    unsigned short* pre = (unsigned short*)(ws + 4096 + 8388608 + 10485760 + 16384);  // 84 MB
    unsigned short* hA = pre + (size_t)8192 * 5120;
    unsigned short* hB = hA + (size_t)8192 * 1024;
    unsigned short* cA = hB + (size_t)8192 * 1024;
    unsigned short* cB = cA + (size_t)8192 * 1024;

    hipMemsetAsync(flags, 0, 4096, stream);

    // layer 0
    conv_inputs_k<<<4096, 256, 0, stream>>>(inputs, A0);
    conv_w_k<<<2048, 256, 0, stream>>>(W_ih0, Wbuf, 512, 0, 512, 4096 * 128);
    bias0_k<<<16, 256, 0, stream>>>(b_ih0, b_hh0, bc0);
    proj_gemm_k<<<dim3(64, 32), 256, 0, stream>>>(A0, Wbuf, bc0, pre, 512, 4096);
    rec_k<4, false, false><<<256, 256, 0, stream>>>(W_hh0, 1024, 0, pre, 4096, nullptr,
                                                    hA, cA, nullptr, nullptr, flags + 0);
    // layer 1
    conv_w_k<<<5120, 256, 0, stream>>>(W_ca + (size_t)0 * 5120 * 2048, Wbuf, 2048, 0, 1024, 5120 * 256);
    proj_gemm_k<<<dim3(64, 40), 256, 0, stream>>>(hA, Wbuf, b_ca + 0 * 5120, pre, 1024, 5120);
    rec_k<5, true, false><<<256, 256, 0, stream>>>(W_ca + (size_t)0 * 5120 * 2048, 2048, 1024, pre, 5120,
                                                   cA, hB, cB, nullptr, nullptr, flags + 256);
    // layer 2
    conv_w_k<<<5120, 256, 0, stream>>>(W_ca + (size_t)1 * 5120 * 2048, Wbuf, 2048, 0, 1024, 5120 * 256);
    proj_gemm_k<<<dim3(64, 40), 256, 0, stream>>>(hB, Wbuf, b_ca + 1 * 5120, pre, 1024, 5120);
    rec_k<5, true, false><<<256, 256, 0, stream>>>(W_ca + (size_t)1 * 5120 * 2048, 2048, 1024, pre, 5120,
                                                   cB, hA, cA, nullptr, nullptr, flags + 512);
    // layer 3 (writes d_out directly: hs then cs, (B,T,H) fp32)
    conv_w_k<<<5120, 256, 0, stream>>>(W_ca + (size_t)2 * 5120 * 2048, Wbuf, 2048, 0, 1024, 5120 * 256);
    proj_gemm_k<<<dim3(64, 40), 256, 0, stream>>>(hA, Wbuf, b_ca + 2 * 5120, pre, 1024, 5120);
    rec_k<5, true, true><<<256, 256, 0, stream>>>(W_ca + (size_t)2 * 5120 * 2048, 2048, 1024, pre, 5120,
                                                  cA, hB, nullptr, out, out + (size_t)8192 * 1024, flags + 768);
}

// Round 3
// 7791.593 us; speedup vs baseline: 1.6197x; 1.0046x over previous
//
#include <hip/hip_runtime.h>
#include <stdint.h>

#define B_ 32
#define T_ 256
#define DI_ 512
#define H_ 1024

using f32x4 = __attribute__((ext_vector_type(4))) float;
using s16x8 = __attribute__((ext_vector_type(8))) short;

__device__ inline unsigned short f2bf(float x) {
    unsigned u = __float_as_uint(x);
    u += 0x7FFFu + ((u >> 16) & 1u);
    return (unsigned short)(u >> 16);
}
__device__ inline float bf2f(unsigned short h) { return __uint_as_float(((unsigned)h) << 16); }
__device__ inline float sigf(float x) { return 1.f / (1.f + __expf(-x)); }
__device__ inline float tanhf_(float x) { return 1.f - 2.f / (__expf(2.f * x) + 1.f); }

// ---------------- conversion kernels ----------------

// inputs (B,T,DI) fp32 -> A0 [(t*B+b)][DI] bf16
__global__ void conv_inputs_k(const float* __restrict__ in, unsigned short* __restrict__ out) {
    int idx = blockIdx.x * 256 + threadIdx.x;
    int d = (idx & 127) * 4;
    int row = idx >> 7;
    int t = row >> 5, b = row & 31;
    float4 v = *(const float4*)(in + ((size_t)b * T_ + t) * DI_ + d);
    unsigned long long p = (unsigned long long)f2bf(v.x)
        | ((unsigned long long)f2bf(v.y) << 16)
        | ((unsigned long long)f2bf(v.z) << 32)
        | ((unsigned long long)f2bf(v.w) << 48);
    *(unsigned long long*)(out + (size_t)row * DI_ + d) = p;
}

// generic fp32 [R][rowStride] (col offset) -> bf16 [R][K]
__global__ void conv_w_k(const float* __restrict__ src, unsigned short* __restrict__ dst,
                         int rowStride, int colOff, int K, int total4) {
    int idx = blockIdx.x * 256 + threadIdx.x;
    if (idx >= total4) return;
    int K4 = K >> 2;
    int r = idx / K4;
    int k = (idx - r * K4) << 2;
    float4 v = *(const float4*)(src + (size_t)r * rowStride + colOff + k);
    unsigned long long p = (unsigned long long)f2bf(v.x)
        | ((unsigned long long)f2bf(v.y) << 16)
        | ((unsigned long long)f2bf(v.z) << 32)
        | ((unsigned long long)f2bf(v.w) << 48);
    *(unsigned long long*)(dst + (size_t)r * K + k) = p;
}

__global__ void bias0_k(const float* __restrict__ a, const float* __restrict__ b, float* __restrict__ o) {
    int i = blockIdx.x * 256 + threadIdx.x;
    if (i < 4 * H_) o[i] = a[i] + b[i];
}

// ---------------- big parallel projection GEMM ----------------
__global__ __launch_bounds__(256) void proj_gemm_k(
    const unsigned short* __restrict__ A, const unsigned short* __restrict__ W,
    const float* __restrict__ bias, unsigned short* __restrict__ out, int K, int N) {
    __shared__ unsigned short Al[128 * 56];
    __shared__ unsigned short Bl[128 * 56];
    const int tid = threadIdx.x;
    const int lane = tid & 63, wave = tid >> 6;
    const int quad = lane >> 4, l16 = lane & 15;
    const int wm = (wave >> 1) * 64, wn = (wave & 1) * 64;
    const int bm = blockIdx.x, bn = blockIdx.y;
    const int srow = tid >> 1, shalf = tid & 1;
    const unsigned short* Ab = A + (size_t)(bm * 128 + srow) * K + shalf * 16;
    const unsigned short* Wb = W + (size_t)(bn * 128 + srow) * K + shalf * 16;

    f32x4 acc[4][4];
#pragma unroll
    for (int i = 0; i < 4; i++)
#pragma unroll
        for (int j = 0; j < 4; j++) acc[i][j] = (f32x4){0.f, 0.f, 0.f, 0.f};

    for (int kb = 0; kb < K; kb += 32) {
        s16x8 a0 = *(const s16x8*)(Ab + kb);
        s16x8 a1 = *(const s16x8*)(Ab + kb + 8);
        s16x8 b0 = *(const s16x8*)(Wb + kb);
        s16x8 b1 = *(const s16x8*)(Wb + kb + 8);
        __syncthreads();
        *(s16x8*)(&Al[srow * 56 + shalf * 16]) = a0;
        *(s16x8*)(&Al[srow * 56 + shalf * 16 + 8]) = a1;
        *(s16x8*)(&Bl[srow * 56 + shalf * 16]) = b0;
        *(s16x8*)(&Bl[srow * 56 + shalf * 16 + 8]) = b1;
        __syncthreads();
        s16x8 af[4], bf[4];
#pragma unroll
        for (int mt = 0; mt < 4; mt++) af[mt] = *(const s16x8*)(&Al[(wm + mt * 16 + l16) * 56 + quad * 8]);
#pragma unroll
        for (int nt = 0; nt < 4; nt++) bf[nt] = *(const s16x8*)(&Bl[(wn + nt * 16 + l16) * 56 + quad * 8]);
#pragma unroll
        for (int mt = 0; mt < 4; mt++)
#pragma unroll
            for (int nt = 0; nt < 4; nt++)
                acc[mt][nt] = __builtin_amdgcn_mfma_f32_16x16x32_bf16(af[mt], bf[nt], acc[mt][nt], 0, 0, 0);
    }
#pragma unroll
    for (int nt = 0; nt < 4; nt++) {
        int col = bn * 128 + wn + nt * 16 + l16;
        float bv = bias[col];
#pragma unroll
        for (int mt = 0; mt < 4; mt++) {
#pragma unroll
            for (int r = 0; r < 4; r++) {
                int rowg = bm * 128 + wm + mt * 16 + quad * 4 + r;
                out[(size_t)rowg * N + col] = f2bf(acc[mt][nt][r] + bv);
            }
        }
    }
}

// ---------------- persistent recurrence kernel (fence-free) ----------------
// h-exchange coherence: producers store h with sc1 (agent) -> LLC; release via
// s_waitcnt vmcnt(0) then sc1 flag store. Consumers poll flags with sc1 loads;
// h staging uses PLAIN cached loads (fresh region each t, first touch is
// post-flag -> no stale copy possible; XCD L2 de-duplicates the broadcast).
//
// Step-barrier contention control (R3):
//  - ONLY wave 0 polls the 256 global flags (4 coalesced 4B atomic loads per
//    lane + s_sleep backoff); waves 1-3 spin on an LDS epoch word. ~8x less
//    read pressure on the 8 hot flag lines -> producer flag stores are not
//    queued behind poll reads (the straggler-tail mechanism).
//  - Release is done by WAVE 3, whose vmcnt at that point covers only its own
//    32x8B h stores. (Wave 0/1 hold the next-step HBM prefetch loads; draining
//    those in the release path cost ~0.3-0.4us/step.)
template <int NG, bool CA, bool WROUT>
__global__ __launch_bounds__(256) void rec_k(
    const float* __restrict__ Wsrc, int wRowStride, int wColOff,
    const unsigned short* __restrict__ pre, int N,
    const unsigned short* __restrict__ clow,
    unsigned short* __restrict__ hbuf,
    unsigned short* __restrict__ cbuf,
    float* __restrict__ outh, float* __restrict__ outc,
    unsigned* __restrict__ flags) {
    constexpr int ROWS = NG * 4;
    __shared__ unsigned short wl[(ROWS + 1) * 1032];
    __shared__ unsigned short hl[32 * 1032];   // staged h(t-1), padded stride
    __shared__ float gl[32 * 25];
    __shared__ alignas(8) unsigned short hsh[128];
    __shared__ unsigned epoch;
    const int tid = threadIdx.x;
    const int wg = blockIdx.x;
    const int lane = tid & 63, wave = tid >> 6;
    const int quad = lane >> 4, l16 = lane & 15;

    if (tid == 0) epoch = 0;

    // load + convert this WG's weight rows into LDS
    for (int i = tid; i < ROWS * 1024; i += 256) {
        int r = i >> 10, k = i & 1023;
        int g = r >> 2, u2 = r & 3;
        float wv = Wsrc[(size_t)(g * H_ + wg * 4 + u2) * wRowStride + wColOff + k];
        wl[r * 1032 + k] = f2bf(wv);
    }
    for (int k = tid; k < 1032; k += 256) wl[ROWS * 1032 + k] = 0;

    const int mtile = wave & 1;
    const int ntile = wave >> 1;
    const bool active = (ntile * 16) < ROWS;
    int brow = ntile * 16 + l16;
    if (brow >= ROWS) brow = ROWS;  // zero row for padded N-columns

    // staging geometry: wave covers h cols [wave*256, wave*256+256)
    const int scol = wave * 256 + (lane & 31) * 8;
    const int srow0 = lane >> 5;

    const int u = tid & 3, b = tid >> 2;  // pointwise ownership (tid < 128)
    const int unit = wg * 4 + u;
    float cst = 0.f;
    unsigned short pg[NG];
    unsigned short clw = 0;
    if (tid < 128) {
#pragma unroll
        for (int g = 0; g < NG; g++) pg[g] = pre[(size_t)b * N + g * H_ + unit];
        if (CA) clw = clow[(size_t)b * H_ + unit];
    }
    __syncthreads();  // wl + epoch ready

    for (int t = 0; t < T_; ++t) {
        if (t > 0) {
            unsigned tgt = (unsigned)t;
            if (wave == 0) {
                // wave 0 covers ALL 256 flags: 4 coalesced 4B loads per lane
                for (;;) {
                    unsigned f0 = __hip_atomic_load(flags + lane, __ATOMIC_RELAXED, __HIP_MEMORY_SCOPE_AGENT);
                    unsigned f1 = __hip_atomic_load(flags + 64 + lane, __ATOMIC_RELAXED, __HIP_MEMORY_SCOPE_AGENT);
                    unsigned f2 = __hip_atomic_load(flags + 128 + lane, __ATOMIC_RELAXED, __HIP_MEMORY_SCOPE_AGENT);
                    unsigned f3 = __hip_atomic_load(flags + 192 + lane, __ATOMIC_RELAXED, __HIP_MEMORY_SCOPE_AGENT);
                    unsigned m01 = f0 < f1 ? f0 : f1;
                    unsigned m23 = f2 < f3 ? f2 : f3;
                    unsigned mn = m01 < m23 ? m01 : m23;
                    if (__all((int)(mn >= tgt))) break;
                    __builtin_amdgcn_s_sleep(4);
                }
                __hip_atomic_store(&epoch, tgt, __ATOMIC_RELAXED, __HIP_MEMORY_SCOPE_WORKGROUP);
            } else {
                while (__hip_atomic_load(&epoch, __ATOMIC_RELAXED, __HIP_MEMORY_SCOPE_WORKGROUP) < tgt)
                    __builtin_amdgcn_s_sleep(1);
            }
            asm volatile("" ::: "memory");  // keep h loads after poll
            // stage this wave's slice of h(t-1) into LDS (plain cached loads)
            const unsigned short* hbase = hbuf + (size_t)(t - 1) * (B_ * H_) + scol;
            s16x8 hv[16];
#pragma unroll
            for (int i = 0; i < 16; i++)
                hv[i] = *(const s16x8*)(hbase + (size_t)(srow0 + 2 * i) * H_);
#pragma unroll
            for (int i = 0; i < 16; i++)
                *(s16x8*)(&hl[(srow0 + 2 * i) * 1032 + scol]) = hv[i];
        }
        __syncthreads();  // hl fully staged
        if (t > 0 && active) {
            const unsigned short* arow = &hl[(mtile * 16 + l16) * 1032 + quad * 8];
            const unsigned short* wrow = &wl[brow * 1032 + quad * 8];
            f32x4 a0 = (f32x4){0.f, 0.f, 0.f, 0.f};
            f32x4 a1 = a0, a2 = a0, a3 = a0;
#pragma unroll
            for (int kb = 0; kb < H_; kb += 128) {
                a0 = __builtin_amdgcn_mfma_f32_16x16x32_bf16(*(const s16x8*)(arow + kb), *(const s16x8*)(wrow + kb), a0, 0, 0, 0);
                a1 = __builtin_amdgcn_mfma_f32_16x16x32_bf16(*(const s16x8*)(arow + kb + 32), *(const s16x8*)(wrow + kb + 32), a1, 0, 0, 0);
                a2 = __builtin_amdgcn_mfma_f32_16x16x32_bf16(*(const s16x8*)(arow + kb + 64), *(const s16x8*)(wrow + kb + 64), a2, 0, 0, 0);
                a3 = __builtin_amdgcn_mfma_f32_16x16x32_bf16(*(const s16x8*)(arow + kb + 96), *(const s16x8*)(wrow + kb + 96), a3, 0, 0, 0);
            }
            f32x4 acc = (a0 + a1) + (a2 + a3);
            int n = ntile * 16 + l16;
            if (n < ROWS) {
#pragma unroll
                for (int r = 0; r < 4; r++) gl[(mtile * 16 + quad * 4 + r) * 25 + n] = acc[r];
            }
        }
        __syncthreads();  // gl ready
        if (tid < 128) {
            float gate[NG];
#pragma unroll
            for (int g = 0; g < NG; g++)
                gate[g] = bf2f(pg[g]) + ((t > 0) ? gl[b * 25 + g * 4 + u] : 0.f);
            float clv = CA ? bf2f(clw) : 0.f;
            if (t + 1 < T_) {  // prefetch next step's pre / c_low (waves 0-1 only)
#pragma unroll
                for (int g = 0; g < NG; g++) pg[g] = pre[(size_t)((t + 1) * B_ + b) * N + g * H_ + unit];
                if (CA) clw = clow[(size_t)((t + 1) * B_ + b) * H_ + unit];
            }
            float cnew, hval;
            if (CA) {
                float iv = sigf(gate[0]);
                float fp = sigf(gate[1] + 1.f);
                float fl = sigf(gate[2] + 1.f);
                float uu = tanhf_(gate[3]);
                float ov = sigf(gate[4]);
                cnew = cst * fp + clv * fl + uu * iv;
                hval = ov * tanhf_(cnew);
            } else {
                float iv = sigf(gate[0]);
                float fv = sigf(gate[1]);
                float gv = tanhf_(gate[2]);
                float ov = sigf(gate[3]);
                cnew = fv * cst + iv * gv;
                hval = ov * tanhf_(cnew);
            }
            cst = cnew;
            hsh[tid] = f2bf(hval);
            size_t ridx = ((size_t)t * B_ + b) * H_ + unit;
            if (cbuf) cbuf[ridx] = f2bf(cnew);  // plain store: consumed by a later dispatch only
            if (WROUT) {
                outh[((size_t)b * T_ + t) * H_ + unit] = hval;
                outc[((size_t)b * T_ + t) * H_ + unit] = cnew;
            }
        }
        __syncthreads();  // hsh ready
        // WAVE 3 release: pack 4 bf16 -> 8B coherent store, drain ONLY its own
        // stores via vmcnt(0), then publish flag.
        if (wave == 3) {
            int l = lane;
            if (l < 32) {
                unsigned long long pk = *(const unsigned long long*)(&hsh[l * 4]);
                unsigned long long* dst = (unsigned long long*)(hbuf + ((size_t)t * B_ + l) * H_ + wg * 4);
                __hip_atomic_store(dst, pk, __ATOMIC_RELAXED, __HIP_MEMORY_SCOPE_AGENT);
            }
            asm volatile("s_waitcnt vmcnt(0)" ::: "memory");  // h stores visible at LLC
            if (l == 0)
                __hip_atomic_store(&flags[wg], (unsigned)(t + 1), __ATOMIC_RELAXED, __HIP_MEMORY_SCOPE_AGENT);
        }
    }
}

// ---------------- launcher ----------------

extern "C" void kernel_launch(void* const* d_in, const int* in_sizes, int n_in,
                              void* d_out, int out_size, void* d_ws, size_t ws_size,
                              hipStream_t stream) {
    const float* inputs = (const float*)d_in[0];
    const float* W_ih0 = (const float*)d_in[1];
    const float* W_hh0 = (const float*)d_in[2];
    const float* b_ih0 = (const float*)d_in[3];
    const float* b_hh0 = (const float*)d_in[4];
    const float* W_ca = (const float*)d_in[5];
    const float* b_ca = (const float*)d_in[6];
    float* out = (float*)d_out;

    char* ws = (char*)d_ws;
    unsigned* flags = (unsigned*)(ws);                                       //  4 KB
    unsigned short* A0 = (unsigned short*)(ws + 4096);                       //  8 MB
    unsigned short* Wbuf = (unsigned short*)(ws + 4096 + 8388608);           // 10.5 MB
    float* bc0 = (float*)(ws + 4096 + 8388608 + 10485760);                   // 16 KB
    unsigned short* pre = (unsigned short*)(ws + 4096 + 8388608 + 10485760 + 16384);  // 84 MB
    unsigned short* hA = pre + (size_t)8192 * 5120;
    unsigned short* hB = hA + (size_t)8192 * 1024;
    unsigned short* cA = hB + (size_t)8192 * 1024;
    unsigned short* cB = cA + (size_t)8192 * 1024;

    hipMemsetAsync(flags, 0, 4096, stream);

    // layer 0
    conv_inputs_k<<<4096, 256, 0, stream>>>(inputs, A0);
    conv_w_k<<<2048, 256, 0, stream>>>(W_ih0, Wbuf, 512, 0, 512, 4096 * 128);
    bias0_k<<<16, 256, 0, stream>>>(b_ih0, b_hh0, bc0);
    proj_gemm_k<<<dim3(64, 32), 256, 0, stream>>>(A0, Wbuf, bc0, pre, 512, 4096);
    rec_k<4, false, false><<<256, 256, 0, stream>>>(W_hh0, 1024, 0, pre, 4096, nullptr,
                                                    hA, cA, nullptr, nullptr, flags + 0);
    // layer 1
    conv_w_k<<<5120, 256, 0, stream>>>(W_ca + (size_t)0 * 5120 * 2048, Wbuf, 2048, 0, 1024, 5120 * 256);
    proj_gemm_k<<<dim3(64, 40), 256, 0, stream>>>(hA, Wbuf, b_ca + 0 * 5120, pre, 1024, 5120);
    rec_k<5, true, false><<<256, 256, 0, stream>>>(W_ca + (size_t)0 * 5120 * 2048, 2048, 1024, pre, 5120,
                                                   cA, hB, cB, nullptr, nullptr, flags + 256);
    // layer 2
    conv_w_k<<<5120, 256, 0, stream>>>(W_ca + (size_t)1 * 5120 * 2048, Wbuf, 2048, 0, 1024, 5120 * 256);
    proj_gemm_k<<<dim3(64, 40), 256, 0, stream>>>(hB, Wbuf, b_ca + 1 * 5120, pre, 1024, 5120);
    rec_k<5, true, false><<<256, 256, 0, stream>>>(W_ca + (size_t)1 * 5120 * 2048, 2048, 1024, pre, 5120,
                                                   cB, hA, cA, nullptr, nullptr, flags + 512);
    // layer 3 (writes d_out directly: hs then cs, (B,T,H) fp32)
    conv_w_k<<<5120, 256, 0, stream>>>(W_ca + (size_t)2 * 5120 * 2048, Wbuf, 2048, 0, 1024, 5120 * 256);
    proj_gemm_k<<<dim3(64, 40), 256, 0, stream>>>(hA, Wbuf, b_ca + 2 * 5120, pre, 1024, 5120);
    rec_k<5, true, true><<<256, 256, 0, stream>>>(W_ca + (size_t)2 * 5120 * 2048, 2048, 1024, pre, 5120,
                                                  cA, hB, nullptr, out, out + (size_t)8192 * 1024, flags + 768);
}